// Round 5
// baseline (553.254 us; speedup 1.0000x reference)
//
#include <hip/hip_runtime.h>
#include <hip/hip_bf16.h>
#include <math.h>

// R8: fragment-register ROTATION in k_gemm8. R2/R4 both stalled at ~200us /
// MfmaUtil 21% regardless of waitcnt scheme; remaining per-body stall ~1400cy.
// Theory: WAR hazard -- each body's ds_reads target the SAME VGPRs the
// previous body's 16-MFMA cluster (512cy pipe occupancy) is still reading,
// so DS write-back stalls and (in-order DS returns) delays every lgkm drain.
// Fix: A-frags rotate 4-deep (a0..a3; body b reads a[b+1&3], MFMAs a[b]) so
// read targets are disjoint from prev AND current MFMA operands. B ping-pong
// (b0/b1) verified already hazard-free. LGKM/VMC ledgers count-identical R4.
typedef __attribute__((ext_vector_type(8))) short  short8;   // 8 bf16 (16 B)
typedef __attribute__((ext_vector_type(4))) float  floatx4;  // MFMA C/D frag
typedef __attribute__((ext_vector_type(4))) int    i32x4;

__device__ __forceinline__ ushort f2bf(float f) {
    __hip_bfloat16 hb = __float2bfloat16(f);  // round-to-nearest-even
    return *(ushort*)&hb;
}
__device__ __forceinline__ short8 pack8(float4 a, float4 b) {
    union { short8 v; ushort u[8]; } r;
    r.u[0] = f2bf(a.x); r.u[1] = f2bf(a.y); r.u[2] = f2bf(a.z); r.u[3] = f2bf(a.w);
    r.u[4] = f2bf(b.x); r.u[5] = f2bf(b.y); r.u[6] = f2bf(b.z); r.u[7] = f2bf(b.w);
    return r.v;
}

// async global->LDS, 16 B per lane. LDS dest wave-uniform base + lane*16.
typedef __attribute__((address_space(1))) const void* gas1_t;
typedef __attribute__((address_space(3))) void*       las3_t;
__device__ __forceinline__ void gload16(const void* g, void* l) {
    __builtin_amdgcn_global_load_lds((gas1_t)g, (las3_t)l, 16, 0, 0);
}
// raw ds_read_b128; lgkmcnt managed manually (rule 18: wait + sched_barrier).
__device__ __forceinline__ short8 ds_read16(uint off) {
    union { i32x4 i; short8 s; } u;
    asm volatile("ds_read_b128 %0, %1" : "=v"(u.i) : "v"(off));
    return u.s;
}

// ---------------------------------------------------------------------------
// fp32 -> bf16 bulk convert. n8 = elements/8 (exact multiples here).
__global__ __launch_bounds__(256) void k_cvt(const float* __restrict__ in,
                                             ushort* __restrict__ out, int n8) {
    int i = blockIdx.x * 256 + threadIdx.x;
    if (i >= n8) return;
    const float4* p = reinterpret_cast<const float4*>(in) + (size_t)i * 2;
    float4 a = p[0], b = p[1];
    *reinterpret_cast<short8*>(out + (size_t)i * 8) = pack8(a, b);
}

// ---------------------------------------------------------------------------
// fc1_w fp32 [4096 d][1024 s] -> fc1T bf16 [1024 s][4096 d]. 64x64 tiles.
__global__ __launch_bounds__(256) void k_transpose(const float* __restrict__ in,
                                                   ushort* __restrict__ out) {
    __shared__ float sm[64][65];
    const int tid = threadIdx.x;
    const int s0 = blockIdx.x * 64;
    const int d0 = blockIdx.y * 64;
#pragma unroll
    for (int i = 0; i < 4; ++i) {
        int lin = i * 256 + tid;
        int dr  = lin >> 4;
        int sc4 = lin & 15;
        float4 v = *reinterpret_cast<const float4*>(&in[(size_t)(d0 + dr) * 1024 + s0 + sc4 * 4]);
        sm[dr][sc4 * 4 + 0] = v.x; sm[dr][sc4 * 4 + 1] = v.y;
        sm[dr][sc4 * 4 + 2] = v.z; sm[dr][sc4 * 4 + 3] = v.w;
    }
    __syncthreads();
#pragma unroll
    for (int i = 0; i < 8; ++i) {
        int lin = i * 256 + tid;
        int dc2 = lin & 31;
        int sr  = lin >> 5;
        uint lo = (uint)f2bf(sm[dc2 * 2][sr]);
        uint hi = (uint)f2bf(sm[dc2 * 2 + 1][sr]);
        *reinterpret_cast<uint*>(&out[(size_t)(s0 + sr) * 4096 + d0 + dc2 * 2]) = lo | (hi << 16);
    }
}

// ---------------------------------------------------------------------------
// bf16 GEMM (m97 structure): C[m][n] = sum_k A[m][k]*B[n][k]. BK=32, 4 waves.
// EPI=0: ((acc+bias[t])*mask[s][t]) -> attnT[t][s] bf16
// EPI=2: K-split partial (blockIdx.z): raw fp32 -> P[sp][s][t], COALESCED.
template <int BM, int BN, int EPI, int SWZ>
__global__ __launch_bounds__(256) void k_gemm_b(const ushort* __restrict__ A,
                                                const ushort* __restrict__ B,
                                                const float* __restrict__ bias,
                                                const float* __restrict__ mask,
                                                void* __restrict__ Cout,
                                                int lda, int ldb, int ksteps) {
    __shared__ ushort As[BM * 32];
    __shared__ ushort Bs[BN * 32];
    const int tid  = threadIdx.x;
    const int wave = tid >> 6, lane = tid & 63;
    const int wm = wave >> 1, wn = wave & 1;
    const int quad = lane >> 4, m16 = lane & 15;

    if (EPI == 2) {
        const int sp = blockIdx.z;
        A += (size_t)sp * 1024;
        B += (size_t)sp * 1024;
        Cout = (void*)((float*)Cout + (size_t)sp * 1048576);
    }

    int bx = blockIdx.x, by = blockIdx.y;
    if (SWZ) {
        const int nx   = gridDim.x;
        const int nwg  = nx * gridDim.y;
        const int orig = by * nx + bx;
        const int cpx  = nwg >> 3;
        const int w    = (orig & 7) * cpx + (orig >> 3);
        bx = w % nx; by = w / nx;
    }
    const int n0 = bx * BN;
    const int m0 = by * BM;

    constexpr int AI = BM / 32;
    constexpr int BJ = BN / 32;
    floatx4 acc[AI][BJ];
    const floatx4 zero = {0.f, 0.f, 0.f, 0.f};
#pragma unroll
    for (int i = 0; i < AI; ++i)
#pragma unroll
        for (int j = 0; j < BJ; ++j) acc[i][j] = zero;

    const int gr = lane >> 2;
    const int gc = (lane & 3) * 8;

    for (int kt = 0; kt < ksteps; ++kt) {
        const int k0 = kt * 32;
        if (kt) __syncthreads();
#pragma unroll
        for (int t = 0; t < BM / 64; ++t) {
            const int r = wave * (BM / 4) + t * 16;
            gload16(&A[(size_t)(m0 + r + gr) * lda + k0 + gc], &As[r * 32]);
        }
#pragma unroll
        for (int t = 0; t < BN / 64; ++t) {
            const int r = wave * (BN / 4) + t * 16;
            gload16(&B[(size_t)(n0 + r + gr) * ldb + k0 + gc], &Bs[r * 32]);
        }
        __syncthreads();

        short8 aF[AI], bF[BJ];
#pragma unroll
        for (int i = 0; i < AI; ++i)
            aF[i] = *reinterpret_cast<const short8*>(&As[(wm * (BM / 2) + i * 16 + m16) * 32 + quad * 8]);
#pragma unroll
        for (int j = 0; j < BJ; ++j)
            bF[j] = *reinterpret_cast<const short8*>(&Bs[(wn * (BN / 2) + j * 16 + m16) * 32 + quad * 8]);
#pragma unroll
        for (int i = 0; i < AI; ++i)
#pragma unroll
            for (int j = 0; j < BJ; ++j)
                acc[i][j] = __builtin_amdgcn_mfma_f32_16x16x32_bf16(aF[i], bF[j], acc[i][j], 0, 0, 0);
    }

    // C/D layout (verified m89/m91): col = lane&15, row = quad*4 + reg
#pragma unroll
    for (int i = 0; i < AI; ++i) {
#pragma unroll
        for (int j = 0; j < BJ; ++j) {
            const int col = n0 + wn * (BN / 2) + j * 16 + m16;
            float bv = 0.f;
            if (EPI == 0) bv = bias[col];
#pragma unroll
            for (int rr = 0; rr < 4; ++rr) {
                const int row = m0 + wm * (BM / 2) + i * 16 + quad * 4 + rr;
                float v = acc[i][j][rr];
                if (EPI == 0) {
                    v = (v + bv) * mask[(size_t)row * 1024 + col];
                    ((ushort*)Cout)[(size_t)col * 1024 + row] = f2bf(v);
                } else {
                    ((float*)Cout)[(size_t)row * 1024 + col] = v;  // P[s][t] coalesced
                }
            }
        }
    }
}

// ---------------------------------------------------------------------------
// attn finish (LDS transpose): attnT[t][s] = bf16((sum_sp P[sp][s][t] + bias[t])
// * mask[s][t]).  64x64 tiles; all global accesses coalesced along t / s.
__global__ __launch_bounds__(256) void k_attn_fin(const float* __restrict__ P,
                                                  const float* __restrict__ bias,
                                                  const float* __restrict__ mask,
                                                  ushort* __restrict__ attnT) {
    __shared__ float sm[64][65];
    const int tid = threadIdx.x;
    const int s0 = blockIdx.x * 64;
    const int t0 = blockIdx.y * 64;
#pragma unroll
    for (int i = 0; i < 4; ++i) {
        int lin = i * 256 + tid;
        int sr  = lin >> 4;          // s within tile
        int tc4 = lin & 15;          // float4 along t
        const size_t off = (size_t)(s0 + sr) * 1024 + t0 + tc4 * 4;
        float4 acc4 = *reinterpret_cast<const float4*>(&P[off]);
#pragma unroll
        for (int sp = 1; sp < 4; ++sp) {
            float4 v = *reinterpret_cast<const float4*>(&P[(size_t)sp * 1048576 + off]);
            acc4.x += v.x; acc4.y += v.y; acc4.z += v.z; acc4.w += v.w;
        }
        float4 bv = *reinterpret_cast<const float4*>(&bias[t0 + tc4 * 4]);
        float4 mk = *reinterpret_cast<const float4*>(&mask[(size_t)(s0 + sr) * 1024 + t0 + tc4 * 4]);
        sm[sr][tc4 * 4 + 0] = (acc4.x + bv.x) * mk.x;
        sm[sr][tc4 * 4 + 1] = (acc4.y + bv.y) * mk.y;
        sm[sr][tc4 * 4 + 2] = (acc4.z + bv.z) * mk.z;
        sm[sr][tc4 * 4 + 3] = (acc4.w + bv.w) * mk.w;
    }
    __syncthreads();
#pragma unroll
    for (int i = 0; i < 8; ++i) {
        int lin = i * 256 + tid;
        int sc2 = lin & 31;          // pairs of s (coalesced store dim)
        int tr  = lin >> 5;          // t within tile
        uint lo = (uint)f2bf(sm[sc2 * 2][tr]);
        uint hi = (uint)f2bf(sm[sc2 * 2 + 1][tr]);
        *reinterpret_cast<uint*>(&attnT[(size_t)(t0 + tr) * 1024 + s0 + sc2 * 2]) = lo | (hi << 16);
    }
}

// ---------------------------------------------------------------------------
// 8-phase 256x256 main GEMM, register-pipelined with 4-deep A-frag rotation.
// M=49152 N=1024 K=1024. 512 thr = 8 waves (2m x 4n), BK=64, NT=16 K-tiles,
// LDS 128 KiB dbuf. Per tile, quadrants (ks,mh): (0,0)(0,1)(1,0)(1,1) use
// a0,a1,a2,a3; body b reads a[(b+1)&3] -- disjoint from prev (a[b-1]) and
// current (a[b]) MFMA operands, killing the DS-writeback WAR stall.
// Ledger (identical counts to R4, verified by induction): BODY1 +4 LGKM(4),
// BODY2 +8 LGKM(8), BODY3 +4 LGKM(4), BODY4 +8(post-BAR) LGKM(8);
// vmcnt(6) at BODY4 leaves 3 HT in flight; slot reuse >=1 barrier separated.
#define SB __builtin_amdgcn_sched_barrier(0)
#define BAR __builtin_amdgcn_s_barrier()
#define LGKM(n) asm volatile("s_waitcnt lgkmcnt(" #n ")")
#define VMC(n)  asm volatile("s_waitcnt vmcnt(" #n ")")

#define RD_A(dst_, base_, ks_, mh_)                                             \
  { _Pragma("unroll")                                                           \
    for (int i_ = 0; i_ < 4; ++i_)                                              \
      dst_[i_] = ds_read16((base_) + (uint)((ks_)*16384 + ((mh_)*4 + i_)*1024)); }
#define RD_B(dst_, base_, ks_)                                                  \
  { _Pragma("unroll")                                                           \
    for (int j_ = 0; j_ < 4; ++j_)                                              \
      dst_[j_] = ds_read16((base_) + (uint)((ks_)*16384 + j_*1024)); }
#define MFMA16(aS_, bS_, MH_)                                                   \
  { __builtin_amdgcn_s_setprio(1);                                              \
    _Pragma("unroll")                                                           \
    for (int i_ = 0; i_ < 4; ++i_) {                                            \
      _Pragma("unroll")                                                         \
      for (int j_ = 0; j_ < 4; ++j_)                                            \
        acc[(MH_)*4 + i_][j_] = __builtin_amdgcn_mfma_f32_16x16x32_bf16(        \
            aS_[i_], bS_[j_], acc[(MH_)*4 + i_][j_], 0, 0, 0);                  \
    }                                                                           \
    __builtin_amdgcn_s_setprio(0); SB; }

// body b: MFMA uses a{b}, reads a{b+1 mod 4}; B: b0 for ks0-bodies, b1 for ks1.
#define BODY1(T_, bA_, bB_)                                                     \
  stage_ht(4*(T_) + 7); RD_A(a1, bA_, 0, 1);                                    \
  SB; BAR; SB; LGKM(4); SB; MFMA16(a0, b0, 0)
#define BODY2(T_, bA_, bB_)                                                     \
  stage_ht(4*(T_) + 8); RD_A(a2, bA_, 1, 0); RD_B(b1, bB_, 1);                  \
  SB; BAR; SB; LGKM(8); SB; MFMA16(a1, b0, 1)
#define BODY3(T_, bA_, bB_)                                                     \
  stage_ht(4*(T_) + 9); RD_A(a3, bA_, 1, 1);                                    \
  SB; BAR; SB; LGKM(4); SB; MFMA16(a2, b1, 0)
#define BODY4(T_, nA_, nB_, G_)                                                 \
  stage_ht(4*(T_) + 10); SB; VMC(G_); SB; BAR; SB;                              \
  RD_A(a0, nA_, 0, 0); RD_B(b0, nB_, 0);                                        \
  SB; LGKM(8); SB; MFMA16(a3, b1, 1)
#define BODY4F()                                                                \
  SB; BAR; SB; LGKM(0); SB; MFMA16(a3, b1, 1)

__global__ __launch_bounds__(512) void k_gemm8(const ushort* __restrict__ A,
                                               const ushort* __restrict__ B,
                                               float* __restrict__ C) {
    constexpr int NT = 16;
    __shared__ __align__(16) ushort lds[65536];   // 128 KiB

    const int tid  = threadIdx.x;
    const int wave = tid >> 6, lane = tid & 63;
    const int wm = wave >> 2, wn = wave & 3;
    const int quad = lane >> 4, m16 = lane & 15;

    // XCD-bijective swizzle, nwg = 768 (96/XCD), n fastest within a chunk.
    const int orig = blockIdx.y * 4 + blockIdx.x;
    const int wsz  = (orig & 7) * 96 + (orig >> 3);
    const int n0 = (wsz & 3) * 256;
    const int m0 = (wsz >> 2) * 256;

    const uint lds0 = (uint)(size_t)(las3_t)(void*)lds;
    const uint xorM = (uint)((m16 & 6) << 3);     // row bits1-2 -> byte bits4-5
    const uint baseA = lds0 + ((((uint)(wm * 128 + m16)) * 64u + (uint)quad * 16u) ^ xorM);
    const uint baseB = lds0 + 32768u + ((((uint)(wn * 64 + m16)) * 64u + (uint)quad * 16u) ^ xorM);

    // staging lane constants: subtile = 1024 B = 16 rows x 64 B; lane -> row
    // lane>>2, chunk swizzled (l&3)^((l>>3)&3) (inverse of the read XOR).
    const int srow   = lane >> 2;
    const int schunk = (((lane & 3) ^ ((lane >> 3) & 3)) << 3);

    auto stage_ht = [&](int g) {
        if (g >= 4 * NT) return;
        const int tg = g >> 2, ig = g & 3;
        const int mat = ig & 1, ks = ig >> 1;
        const int kc  = tg * 64 + ks * 32 + schunk;
        const uint dst0 = (uint)(((tg & 1) << 16) | (mat << 15) | (ks << 14));
        const ushort* src = mat ? B : A;
        const int r0 = (mat ? n0 : m0) + srow;
#pragma unroll
        for (int e = 0; e < 2; ++e) {
            const int s = e * 8 + wave;
            gload16(&src[(size_t)(r0 + s * 16) * 1024 + kc],
                    (void*)((char*)lds + dst0 + (uint)(s << 10)));
        }
    };

    floatx4 acc[8][4];
    const floatx4 zf = {0.f, 0.f, 0.f, 0.f};
#pragma unroll
    for (int i = 0; i < 8; ++i)
#pragma unroll
        for (int j = 0; j < 4; ++j) acc[i][j] = zf;
    short8 a0[4], a1[4], a2[4], a3[4], b0[4], b1[4];

    // prologue: tile0 (4 HT) + tile1 A0,B0,A1 (7 HT = 14 ops); vmcnt(6)
    // drains tile0; then prime phase-1 fragments.
#pragma unroll
    for (int g = 0; g < 7; ++g) stage_ht(g);
    SB; VMC(6); SB; BAR; SB;
    RD_A(a0, baseA, 0, 0);
    RD_B(b0, baseB, 0);

    for (int tp = 0; tp < 7; ++tp) {
        const int t0 = 2 * tp, t1 = 2 * tp + 1;
        const uint cA = baseA, cB = baseB;                    // buf 0
        const uint dA = baseA + 65536u, dB = baseB + 65536u;  // buf 1
        BODY1(t0, cA, cB); BODY2(t0, cA, cB); BODY3(t0, cA, cB);
        BODY4(t0, dA, dB, 6);
        BODY1(t1, dA, dB); BODY2(t1, dA, dB); BODY3(t1, dA, dB);
        BODY4(t1, cA, cB, 6);
    }
    {   // tiles 14 (buf0) and 15 (buf1); stage_ht nops past g=63.
        const uint cA = baseA, cB = baseB;
        const uint dA = baseA + 65536u, dB = baseB + 65536u;
        BODY1(14, cA, cB); BODY2(14, cA, cB); BODY3(14, cA, cB);
        BODY4(14, dA, dB, 0);
        BODY1(15, dA, dB); BODY2(15, dA, dB); BODY3(15, dA, dB);
        BODY4F();
    }

    // epilogue: exact-erf GELU, fp32 store (coalesced along col)
#pragma unroll
    for (int mf = 0; mf < 8; ++mf) {
#pragma unroll
        for (int nf = 0; nf < 4; ++nf) {
            const int col = n0 + wn * 64 + nf * 16 + m16;
#pragma unroll
            for (int rr = 0; rr < 4; ++rr) {
                const int row = m0 + wm * 128 + mf * 16 + quad * 4 + rr;
                const float v = acc[mf][nf][rr];
                C[(size_t)row * 1024 + col] = 0.5f * v * (1.0f + erff(v * 0.70710678118654752f));
            }
        }
    }
}

// ---------------------------------------------------------------------------
// Fallback main GEMM reading fp32 A directly (only if ws can't hold xb).
__global__ __launch_bounds__(256) void k_gemm_f32a(const float* __restrict__ Af,
                                                   const ushort* __restrict__ B,
                                                   float* __restrict__ Cout,
                                                   int lda, int ldb, int ksteps) {
    __shared__ ushort As[128 * 32];
    __shared__ ushort Bs[128 * 32];
    const int tid  = threadIdx.x;
    const int wave = tid >> 6, lane = tid & 63;
    const int wm = wave >> 1, wn = wave & 1;
    const int quad = lane >> 4, m16 = lane & 15;
    const int n0 = blockIdx.x * 128;
    const int m0 = blockIdx.y * 128;

    floatx4 acc[4][4];
    const floatx4 zero = {0.f, 0.f, 0.f, 0.f};
#pragma unroll
    for (int i = 0; i < 4; ++i)
#pragma unroll
        for (int j = 0; j < 4; ++j) acc[i][j] = zero;

    const int s_r = tid >> 2;
    const int s_c = tid & 3;
    const int gr = lane >> 2;
    const int gc = (lane & 3) * 8;

    for (int kt = 0; kt < ksteps; ++kt) {
        const int k0 = kt * 32;
        const float* r0 = &Af[(size_t)(m0 + s_r) * lda + k0 + s_c * 8];
        const float* r1 = &Af[(size_t)(m0 + 64 + s_r) * lda + k0 + s_c * 8];
        short8 a0 = pack8(*reinterpret_cast<const float4*>(r0), *reinterpret_cast<const float4*>(r0 + 4));
        short8 a1 = pack8(*reinterpret_cast<const float4*>(r1), *reinterpret_cast<const float4*>(r1 + 4));
        __syncthreads();
        *reinterpret_cast<short8*>(&As[(s_r)      * 32 + s_c * 8]) = a0;
        *reinterpret_cast<short8*>(&As[(64 + s_r) * 32 + s_c * 8]) = a1;
#pragma unroll
        for (int t = 0; t < 2; ++t) {
            const int r = wave * 32 + t * 16;
            gload16(&B[(size_t)(n0 + r + gr) * ldb + k0 + gc], &Bs[r * 32]);
        }
        __syncthreads();

        short8 aF[4], bF[4];
#pragma unroll
        for (int i = 0; i < 4; ++i)
            aF[i] = *reinterpret_cast<const short8*>(&As[(wm * 64 + i * 16 + m16) * 32 + quad * 8]);
#pragma unroll
        for (int j = 0; j < 4; ++j)
            bF[j] = *reinterpret_cast<const short8*>(&Bs[(wn * 64 + j * 16 + m16) * 32 + quad * 8]);
#pragma unroll
        for (int i = 0; i < 4; ++i)
#pragma unroll
            for (int j = 0; j < 4; ++j)
                acc[i][j] = __builtin_amdgcn_mfma_f32_16x16x32_bf16(aF[i], bF[j], acc[i][j], 0, 0, 0);
    }

#pragma unroll
    for (int i = 0; i < 4; ++i)
#pragma unroll
        for (int j = 0; j < 4; ++j) {
            const int col = n0 + wn * 64 + j * 16 + m16;
#pragma unroll
            for (int rr = 0; rr < 4; ++rr) {
                const int row = m0 + wm * 64 + i * 16 + quad * 4 + rr;
                float v = acc[i][j][rr];
                Cout[(size_t)row * 1024 + col] = 0.5f * v * (1.0f + erff(v * 0.70710678118654752f));
            }
        }
}

// ---------------------------------------------------------------------------
extern "C" void kernel_launch(void* const* d_in, const int* in_sizes, int n_in,
                              void* d_out, int out_size, void* d_ws, size_t ws_size,
                              hipStream_t stream) {
    const float* x    = (const float*)d_in[0];  // [49152][1024] fp32
    const float* fc1w = (const float*)d_in[1];  // [4096][1024]  fp32
    const float* fc2w = (const float*)d_in[2];  // [1024][4096]  fp32
    const float* fc2b = (const float*)d_in[3];  // [1024]        fp32
    const float* mask = (const float*)d_in[4];  // [1024][1024]  fp32, s-major

    char* ws = (char*)d_ws;
    ushort* fc1T  = (ushort*)ws;                  //  8 MiB [1024 s][4096 d] bf16
    ushort* fc2wb = (ushort*)(ws + (8u  << 20));  //  8 MiB [1024 t][4096 d] bf16
    ushort* attnT = (ushort*)(ws + (16u << 20));  //  2 MiB [1024 t][1024 s] bf16
    float*  attnP = (float*)(ws + (18u << 20));   // 16 MiB 4x[1024][1024] fp32 (reused by xb)
    ushort* xb    = (ushort*)(ws + (18u << 20));  // 96 MiB [49152][1024] bf16
    const size_t XB_BYTES = 50331648ull * 2;
    const bool has_xb = ws_size >= (size_t)(18u << 20) + XB_BYTES;
    const bool has_p  = ws_size >= (size_t)(34u << 20);

    // weight prep (small)
    k_transpose<<<dim3(16, 64), 256, 0, stream>>>(fc1w, fc1T);
    k_cvt<<<2048, 256, 0, stream>>>(fc2w, fc2wb, 524288);

    // attn: K-split x4 (1024 wg, coalesced P[sp][s][t] stores) + LDS-transpose
    // finish. attnP region reused by xb AFTER k_attn_fin completes (in-order).
    if (has_p) {
        k_gemm_b<64, 64, 2, 1><<<dim3(16, 16, 4), 256, 0, stream>>>(
            fc1T, fc2wb, nullptr, nullptr, attnP, 4096, 4096, 32);
        k_attn_fin<<<dim3(16, 16), 256, 0, stream>>>(attnP, fc2b, mask, attnT);
    } else {
        k_gemm_b<64, 64, 0, 1><<<dim3(16, 16), 256, 0, stream>>>(
            fc1T, fc2wb, fc2b, mask, attnT, 4096, 4096, 128);
    }

    // main: out[m][t] = gelu(x·attnT^T), fp32 store
    if (has_xb) {
        k_cvt<<<24576, 256, 0, stream>>>(x, xb, 6291456);
        k_gemm8<<<dim3(4, 192), 512, 0, stream>>>(xb, attnT, (float*)d_out);
    } else {
        k_gemm_f32a<<<dim3(8, 384), 256, 0, stream>>>(x, attnT, (float*)d_out, 1024, 1024, 32);
    }
}

// Round 6
// 519.031 us; speedup vs baseline: 1.0659x; 1.0659x over previous
//
#include <hip/hip_runtime.h>
#include <hip/hip_bf16.h>
#include <math.h>

// R9: main GEMM replaced by k_gemm2 — 128x128/BK=64/4-wave, 64KiB LDS so TWO
// blocks co-reside per CU (inter-block TLP replaces intra-block pipelining),
// and only 2 barriers per K-tile. Rationale: R0-R5 all pinned at ~200us with
// every pipe ~20%; common factor was 8+ lockstep barriers/K-tile at 1 block/CU
// (~10k cyc/tile vs ~1.5k of real work). R5's frag rotation reverted (255us).
typedef __attribute__((ext_vector_type(8))) short  short8;   // 8 bf16 (16 B)
typedef __attribute__((ext_vector_type(4))) float  floatx4;  // MFMA C/D frag
typedef __attribute__((ext_vector_type(4))) int    i32x4;

__device__ __forceinline__ ushort f2bf(float f) {
    __hip_bfloat16 hb = __float2bfloat16(f);  // round-to-nearest-even
    return *(ushort*)&hb;
}
__device__ __forceinline__ short8 pack8(float4 a, float4 b) {
    union { short8 v; ushort u[8]; } r;
    r.u[0] = f2bf(a.x); r.u[1] = f2bf(a.y); r.u[2] = f2bf(a.z); r.u[3] = f2bf(a.w);
    r.u[4] = f2bf(b.x); r.u[5] = f2bf(b.y); r.u[6] = f2bf(b.z); r.u[7] = f2bf(b.w);
    return r.v;
}

// async global->LDS, 16 B per lane. LDS dest wave-uniform base (+lane*16 by HW).
typedef __attribute__((address_space(1))) const void* gas1_t;
typedef __attribute__((address_space(3))) void*       las3_t;
__device__ __forceinline__ void gload16(const void* g, void* l) {
    __builtin_amdgcn_global_load_lds((gas1_t)g, (las3_t)l, 16, 0, 0);
}
// raw ds_read_b128; lgkmcnt managed manually (rule 18: wait + sched_barrier).
__device__ __forceinline__ short8 ds_read16(uint off) {
    union { i32x4 i; short8 s; } u;
    asm volatile("ds_read_b128 %0, %1" : "=v"(u.i) : "v"(off));
    return u.s;
}

#define SB __builtin_amdgcn_sched_barrier(0)
#define BAR __builtin_amdgcn_s_barrier()
#define LGKM0 asm volatile("s_waitcnt lgkmcnt(0)")
#define VMC(n)  asm volatile("s_waitcnt vmcnt(" #n ")")

// ---------------------------------------------------------------------------
// fp32 -> bf16 bulk convert. n8 = elements/8 (exact multiples here).
__global__ __launch_bounds__(256) void k_cvt(const float* __restrict__ in,
                                             ushort* __restrict__ out, int n8) {
    int i = blockIdx.x * 256 + threadIdx.x;
    if (i >= n8) return;
    const float4* p = reinterpret_cast<const float4*>(in) + (size_t)i * 2;
    float4 a = p[0], b = p[1];
    *reinterpret_cast<short8*>(out + (size_t)i * 8) = pack8(a, b);
}

// ---------------------------------------------------------------------------
// fc1_w fp32 [4096 d][1024 s] -> fc1T bf16 [1024 s][4096 d]. 64x64 tiles.
__global__ __launch_bounds__(256) void k_transpose(const float* __restrict__ in,
                                                   ushort* __restrict__ out) {
    __shared__ float sm[64][65];
    const int tid = threadIdx.x;
    const int s0 = blockIdx.x * 64;
    const int d0 = blockIdx.y * 64;
#pragma unroll
    for (int i = 0; i < 4; ++i) {
        int lin = i * 256 + tid;
        int dr  = lin >> 4;
        int sc4 = lin & 15;
        float4 v = *reinterpret_cast<const float4*>(&in[(size_t)(d0 + dr) * 1024 + s0 + sc4 * 4]);
        sm[dr][sc4 * 4 + 0] = v.x; sm[dr][sc4 * 4 + 1] = v.y;
        sm[dr][sc4 * 4 + 2] = v.z; sm[dr][sc4 * 4 + 3] = v.w;
    }
    __syncthreads();
#pragma unroll
    for (int i = 0; i < 8; ++i) {
        int lin = i * 256 + tid;
        int dc2 = lin & 31;
        int sr  = lin >> 5;
        uint lo = (uint)f2bf(sm[dc2 * 2][sr]);
        uint hi = (uint)f2bf(sm[dc2 * 2 + 1][sr]);
        *reinterpret_cast<uint*>(&out[(size_t)(s0 + sr) * 4096 + d0 + dc2 * 2]) = lo | (hi << 16);
    }
}

// ---------------------------------------------------------------------------
// bf16 GEMM (m97 structure): C[m][n] = sum_k A[m][k]*B[n][k]. BK=32, 4 waves.
// EPI=0: ((acc+bias[t])*mask[s][t]) -> attnT[t][s] bf16
// EPI=2: K-split partial (blockIdx.z): raw fp32 -> P[sp][s][t], COALESCED.
template <int BM, int BN, int EPI, int SWZ>
__global__ __launch_bounds__(256) void k_gemm_b(const ushort* __restrict__ A,
                                                const ushort* __restrict__ B,
                                                const float* __restrict__ bias,
                                                const float* __restrict__ mask,
                                                void* __restrict__ Cout,
                                                int lda, int ldb, int ksteps) {
    __shared__ ushort As[BM * 32];
    __shared__ ushort Bs[BN * 32];
    const int tid  = threadIdx.x;
    const int wave = tid >> 6, lane = tid & 63;
    const int wm = wave >> 1, wn = wave & 1;
    const int quad = lane >> 4, m16 = lane & 15;

    if (EPI == 2) {
        const int sp = blockIdx.z;
        A += (size_t)sp * 1024;
        B += (size_t)sp * 1024;
        Cout = (void*)((float*)Cout + (size_t)sp * 1048576);
    }

    int bx = blockIdx.x, by = blockIdx.y;
    if (SWZ) {
        const int nx   = gridDim.x;
        const int nwg  = nx * gridDim.y;
        const int orig = by * nx + bx;
        const int cpx  = nwg >> 3;
        const int w    = (orig & 7) * cpx + (orig >> 3);
        bx = w % nx; by = w / nx;
    }
    const int n0 = bx * BN;
    const int m0 = by * BM;

    constexpr int AI = BM / 32;
    constexpr int BJ = BN / 32;
    floatx4 acc[AI][BJ];
    const floatx4 zero = {0.f, 0.f, 0.f, 0.f};
#pragma unroll
    for (int i = 0; i < AI; ++i)
#pragma unroll
        for (int j = 0; j < BJ; ++j) acc[i][j] = zero;

    const int gr = lane >> 2;
    const int gc = (lane & 3) * 8;

    for (int kt = 0; kt < ksteps; ++kt) {
        const int k0 = kt * 32;
        if (kt) __syncthreads();
#pragma unroll
        for (int t = 0; t < BM / 64; ++t) {
            const int r = wave * (BM / 4) + t * 16;
            gload16(&A[(size_t)(m0 + r + gr) * lda + k0 + gc], &As[r * 32]);
        }
#pragma unroll
        for (int t = 0; t < BN / 64; ++t) {
            const int r = wave * (BN / 4) + t * 16;
            gload16(&B[(size_t)(n0 + r + gr) * ldb + k0 + gc], &Bs[r * 32]);
        }
        __syncthreads();

        short8 aF[AI], bF[BJ];
#pragma unroll
        for (int i = 0; i < AI; ++i)
            aF[i] = *reinterpret_cast<const short8*>(&As[(wm * (BM / 2) + i * 16 + m16) * 32 + quad * 8]);
#pragma unroll
        for (int j = 0; j < BJ; ++j)
            bF[j] = *reinterpret_cast<const short8*>(&Bs[(wn * (BN / 2) + j * 16 + m16) * 32 + quad * 8]);
#pragma unroll
        for (int i = 0; i < AI; ++i)
#pragma unroll
            for (int j = 0; j < BJ; ++j)
                acc[i][j] = __builtin_amdgcn_mfma_f32_16x16x32_bf16(aF[i], bF[j], acc[i][j], 0, 0, 0);
    }

    // C/D layout (verified m89/m91): col = lane&15, row = quad*4 + reg
#pragma unroll
    for (int i = 0; i < AI; ++i) {
#pragma unroll
        for (int j = 0; j < BJ; ++j) {
            const int col = n0 + wn * (BN / 2) + j * 16 + m16;
            float bv = 0.f;
            if (EPI == 0) bv = bias[col];
#pragma unroll
            for (int rr = 0; rr < 4; ++rr) {
                const int row = m0 + wm * (BM / 2) + i * 16 + quad * 4 + rr;
                float v = acc[i][j][rr];
                if (EPI == 0) {
                    v = (v + bv) * mask[(size_t)row * 1024 + col];
                    ((ushort*)Cout)[(size_t)col * 1024 + row] = f2bf(v);
                } else {
                    ((float*)Cout)[(size_t)row * 1024 + col] = v;  // P[s][t] coalesced
                }
            }
        }
    }
}

// ---------------------------------------------------------------------------
// attn finish (LDS transpose): attnT[t][s] = bf16((sum_sp P[sp][s][t] + bias[t])
// * mask[s][t]).  64x64 tiles; all global accesses coalesced along t / s.
__global__ __launch_bounds__(256) void k_attn_fin(const float* __restrict__ P,
                                                  const float* __restrict__ bias,
                                                  const float* __restrict__ mask,
                                                  ushort* __restrict__ attnT) {
    __shared__ float sm[64][65];
    const int tid = threadIdx.x;
    const int s0 = blockIdx.x * 64;
    const int t0 = blockIdx.y * 64;
#pragma unroll
    for (int i = 0; i < 4; ++i) {
        int lin = i * 256 + tid;
        int sr  = lin >> 4;          // s within tile
        int tc4 = lin & 15;          // float4 along t
        const size_t off = (size_t)(s0 + sr) * 1024 + t0 + tc4 * 4;
        float4 acc4 = *reinterpret_cast<const float4*>(&P[off]);
#pragma unroll
        for (int sp = 1; sp < 4; ++sp) {
            float4 v = *reinterpret_cast<const float4*>(&P[(size_t)sp * 1048576 + off]);
            acc4.x += v.x; acc4.y += v.y; acc4.z += v.z; acc4.w += v.w;
        }
        float4 bv = *reinterpret_cast<const float4*>(&bias[t0 + tc4 * 4]);
        float4 mk = *reinterpret_cast<const float4*>(&mask[(size_t)(s0 + sr) * 1024 + t0 + tc4 * 4]);
        sm[sr][tc4 * 4 + 0] = (acc4.x + bv.x) * mk.x;
        sm[sr][tc4 * 4 + 1] = (acc4.y + bv.y) * mk.y;
        sm[sr][tc4 * 4 + 2] = (acc4.z + bv.z) * mk.z;
        sm[sr][tc4 * 4 + 3] = (acc4.w + bv.w) * mk.w;
    }
    __syncthreads();
#pragma unroll
    for (int i = 0; i < 8; ++i) {
        int lin = i * 256 + tid;
        int sc2 = lin & 31;          // pairs of s (coalesced store dim)
        int tr  = lin >> 5;          // t within tile
        uint lo = (uint)f2bf(sm[sc2 * 2][tr]);
        uint hi = (uint)f2bf(sm[sc2 * 2 + 1][tr]);
        *reinterpret_cast<uint*>(&attnT[(size_t)(t0 + tr) * 1024 + s0 + sc2 * 2]) = lo | (hi << 16);
    }
}

// ---------------------------------------------------------------------------
// Main GEMM: out[m][t] = gelu(sum_s x[m][s]*attnT[t][s]).
// M=49152 N=1024 K=1024. 128x128 tile, BK=64, 4 waves (2x2), 256 thr.
// LDS = 2 buf x (A 16K + B 16K) = 64 KiB -> 2 blocks/CU (inter-block TLP).
// Per K-tile: VMC(8); BAR; 16 ds_read_b128; LGKM(0); BAR; stage(T+2); 32 MFMA.
// vmcnt ledger: at tile T's VMC(8), in flight = stage(T)+stage(T+1) (8 ea);
// forces T landed, leaves T+1 in flight. T=15 peeled with VMC(0).
// Buffer safety: stage(T+2) hits buf[T&1] (just read); issued only after the
// post-LGKM0 barrier = all waves' reads retired -> no overwrite race.
// LDS swizzle: row r (128 B = 8 chunks of 16 B): phys chunk = c ^ (r&7).
// Staging pre-swizzles the GLOBAL source (rule 21); involution verified.
__global__ __launch_bounds__(256, 2) void k_gemm2(const ushort* __restrict__ A,
                                                  const ushort* __restrict__ B,
                                                  float* __restrict__ C) {
    __shared__ __align__(16) ushort lds[32768];   // 64 KiB
    const int tid  = threadIdx.x;
    const int wave = tid >> 6, lane = tid & 63;
    const int wm = wave >> 1, wn = wave & 1;
    const int quad = lane >> 4, m16 = lane & 15;

    // XCD-bijective swizzle: nwg = 3072 (384/XCD), n fastest within a chunk.
    const int orig = blockIdx.y * 8 + blockIdx.x;
    const int wsz  = (orig & 7) * 384 + (orig >> 3);
    const int n0 = (wsz & 7) * 128;
    const int m0 = (wsz >> 3) * 128;

    const uint lds0 = (uint)(size_t)(las3_t)(void*)lds;
    // fragment read bases: row = w*64 + i*16 + m16; (row&7) == (m16&7).
    const uint cs0 = (uint)(((0 + quad) ^ (m16 & 7)) << 4);   // ks=0 chunk
    const uint cs1 = (uint)(((4 + quad) ^ (m16 & 7)) << 4);   // ks=1 chunk
    const uint ldsA = lds0 + (uint)((wm * 64 + m16) * 128);
    const uint ldsB = lds0 + 16384u + (uint)((wn * 64 + m16) * 128);

    // staging: per wave 4 A + 4 B gloads/tile; instr q = wave*4+t covers rows
    // q*8..q*8+7 linearly in LDS; lane l -> row q*8 + (l>>3), phys chunk l&7,
    // global chunk (l&7)^((l>>3)&7)  (inverse of read swizzle).
    const int srow = lane >> 3;
    const int cswz = (lane & 7) ^ srow;
    const ushort* pA = A + (size_t)(m0 + wave * 32 + srow) * 1024 + cswz * 8;
    const ushort* pB = B + (size_t)(n0 + wave * 32 + srow) * 1024 + cswz * 8;

    auto stage = [&](int T) {
        const uint bo = (uint)(T & 1) << 15;
        const size_t colT = (size_t)T * 64;
        char* dA = (char*)lds + bo + wave * 4096;
        char* dB = (char*)lds + bo + 16384 + wave * 4096;
#pragma unroll
        for (int t = 0; t < 4; ++t)
            gload16(pA + colT + (size_t)t * 8192, dA + t * 1024);
#pragma unroll
        for (int t = 0; t < 4; ++t)
            gload16(pB + colT + (size_t)t * 8192, dB + t * 1024);
    };

    floatx4 acc[4][4];
    const floatx4 zf = {0.f, 0.f, 0.f, 0.f};
#pragma unroll
    for (int i = 0; i < 4; ++i)
#pragma unroll
        for (int j = 0; j < 4; ++j) acc[i][j] = zf;

    stage(0); stage(1);   // 16 gloads/wave in flight

    short8 aF[2][4], bF[2][4];
#define READS(bo_)                                                              \
    { _Pragma("unroll")                                                         \
      for (int i_ = 0; i_ < 4; ++i_) {                                          \
        aF[0][i_] = ds_read16(ldsA + (bo_) + i_ * 2048 + cs0);                  \
        aF[1][i_] = ds_read16(ldsA + (bo_) + i_ * 2048 + cs1);                  \
      }                                                                         \
      _Pragma("unroll")                                                         \
      for (int j_ = 0; j_ < 4; ++j_) {                                          \
        bF[0][j_] = ds_read16(ldsB + (bo_) + j_ * 2048 + cs0);                  \
        bF[1][j_] = ds_read16(ldsB + (bo_) + j_ * 2048 + cs1);                  \
      } }
#define MFMA32                                                                  \
    { __builtin_amdgcn_s_setprio(1);                                            \
      _Pragma("unroll")                                                         \
      for (int ks_ = 0; ks_ < 2; ++ks_)                                         \
        _Pragma("unroll")                                                       \
        for (int i_ = 0; i_ < 4; ++i_)                                          \
          _Pragma("unroll")                                                     \
          for (int j_ = 0; j_ < 4; ++j_)                                        \
            acc[i_][j_] = __builtin_amdgcn_mfma_f32_16x16x32_bf16(              \
                aF[ks_][i_], bF[ks_][j_], acc[i_][j_], 0, 0, 0);                \
      __builtin_amdgcn_s_setprio(0); }

    for (int T = 0; T < 15; ++T) {
        VMC(8); SB; BAR; SB;
        const uint bo = (uint)(T & 1) << 15;
        READS(bo);
        LGKM0; SB; BAR; SB;          // all waves' reads retired -> buf reusable
        if (T < 14) stage(T + 2);
        SB;
        MFMA32; SB;
    }
    // T = 15 (buf 1): no further staging.
    VMC(0); SB; BAR; SB;
    READS(32768u);
    LGKM0; SB;
    MFMA32;

    // epilogue: exact-erf GELU, fp32 store (coalesced along col)
#pragma unroll
    for (int i = 0; i < 4; ++i) {
#pragma unroll
        for (int j = 0; j < 4; ++j) {
            const int col = n0 + wn * 64 + j * 16 + m16;
#pragma unroll
            for (int rr = 0; rr < 4; ++rr) {
                const int row = m0 + wm * 64 + i * 16 + quad * 4 + rr;
                const float v = acc[i][j][rr];
                C[(size_t)row * 1024 + col] = 0.5f * v * (1.0f + erff(v * 0.70710678118654752f));
            }
        }
    }
#undef READS
#undef MFMA32
}

// ---------------------------------------------------------------------------
// Fallback main GEMM reading fp32 A directly (only if ws can't hold xb).
__global__ __launch_bounds__(256) void k_gemm_f32a(const float* __restrict__ Af,
                                                   const ushort* __restrict__ B,
                                                   float* __restrict__ Cout,
                                                   int lda, int ldb, int ksteps) {
    __shared__ ushort As[128 * 32];
    __shared__ ushort Bs[128 * 32];
    const int tid  = threadIdx.x;
    const int wave = tid >> 6, lane = tid & 63;
    const int wm = wave >> 1, wn = wave & 1;
    const int quad = lane >> 4, m16 = lane & 15;
    const int n0 = blockIdx.x * 128;
    const int m0 = blockIdx.y * 128;

    floatx4 acc[4][4];
    const floatx4 zero = {0.f, 0.f, 0.f, 0.f};
#pragma unroll
    for (int i = 0; i < 4; ++i)
#pragma unroll
        for (int j = 0; j < 4; ++j) acc[i][j] = zero;

    const int s_r = tid >> 2;
    const int s_c = tid & 3;
    const int gr = lane >> 2;
    const int gc = (lane & 3) * 8;

    for (int kt = 0; kt < ksteps; ++kt) {
        const int k0 = kt * 32;
        const float* r0 = &Af[(size_t)(m0 + s_r) * lda + k0 + s_c * 8];
        const float* r1 = &Af[(size_t)(m0 + 64 + s_r) * lda + k0 + s_c * 8];
        short8 a0 = pack8(*reinterpret_cast<const float4*>(r0), *reinterpret_cast<const float4*>(r0 + 4));
        short8 a1 = pack8(*reinterpret_cast<const float4*>(r1), *reinterpret_cast<const float4*>(r1 + 4));
        __syncthreads();
        *reinterpret_cast<short8*>(&As[(s_r)      * 32 + s_c * 8]) = a0;
        *reinterpret_cast<short8*>(&As[(64 + s_r) * 32 + s_c * 8]) = a1;
#pragma unroll
        for (int t = 0; t < 2; ++t) {
            const int r = wave * 32 + t * 16;
            gload16(&B[(size_t)(n0 + r + gr) * ldb + k0 + gc], &Bs[r * 32]);
        }
        __syncthreads();

        short8 aF[4], bF[4];
#pragma unroll
        for (int i = 0; i < 4; ++i)
            aF[i] = *reinterpret_cast<const short8*>(&As[(wm * 64 + i * 16 + m16) * 32 + quad * 8]);
#pragma unroll
        for (int j = 0; j < 4; ++j)
            bF[j] = *reinterpret_cast<const short8*>(&Bs[(wn * 64 + j * 16 + m16) * 32 + quad * 8]);
#pragma unroll
        for (int i = 0; i < 4; ++i)
#pragma unroll
            for (int j = 0; j < 4; ++j)
                acc[i][j] = __builtin_amdgcn_mfma_f32_16x16x32_bf16(aF[i], bF[j], acc[i][j], 0, 0, 0);
    }

#pragma unroll
    for (int i = 0; i < 4; ++i)
#pragma unroll
        for (int j = 0; j < 4; ++j) {
            const int col = n0 + wn * 64 + j * 16 + m16;
#pragma unroll
            for (int rr = 0; rr < 4; ++rr) {
                const int row = m0 + wm * 64 + i * 16 + quad * 4 + rr;
                float v = acc[i][j][rr];
                Cout[(size_t)row * 1024 + col] = 0.5f * v * (1.0f + erff(v * 0.70710678118654752f));
            }
        }
}

// ---------------------------------------------------------------------------
extern "C" void kernel_launch(void* const* d_in, const int* in_sizes, int n_in,
                              void* d_out, int out_size, void* d_ws, size_t ws_size,
                              hipStream_t stream) {
    const float* x    = (const float*)d_in[0];  // [49152][1024] fp32
    const float* fc1w = (const float*)d_in[1];  // [4096][1024]  fp32
    const float* fc2w = (const float*)d_in[2];  // [1024][4096]  fp32
    const float* fc2b = (const float*)d_in[3];  // [1024]        fp32
    const float* mask = (const float*)d_in[4];  // [1024][1024]  fp32, s-major

    char* ws = (char*)d_ws;
    ushort* fc1T  = (ushort*)ws;                  //  8 MiB [1024 s][4096 d] bf16
    ushort* fc2wb = (ushort*)(ws + (8u  << 20));  //  8 MiB [1024 t][4096 d] bf16
    ushort* attnT = (ushort*)(ws + (16u << 20));  //  2 MiB [1024 t][1024 s] bf16
    float*  attnP = (float*)(ws + (18u << 20));   // 16 MiB 4x[1024][1024] fp32 (reused by xb)
    ushort* xb    = (ushort*)(ws + (18u << 20));  // 96 MiB [49152][1024] bf16
    const size_t XB_BYTES = 50331648ull * 2;
    const bool has_xb = ws_size >= (size_t)(18u << 20) + XB_BYTES;
    const bool has_p  = ws_size >= (size_t)(34u << 20);

    // weight prep (small)
    k_transpose<<<dim3(16, 64), 256, 0, stream>>>(fc1w, fc1T);
    k_cvt<<<2048, 256, 0, stream>>>(fc2w, fc2wb, 524288);

    // attn: K-split x4 (1024 wg, coalesced P[sp][s][t] stores) + LDS-transpose
    // finish. attnP region reused by xb AFTER k_attn_fin completes (in-order).
    if (has_p) {
        k_gemm_b<64, 64, 2, 1><<<dim3(16, 16, 4), 256, 0, stream>>>(
            fc1T, fc2wb, nullptr, nullptr, attnP, 4096, 4096, 32);
        k_attn_fin<<<dim3(16, 16), 256, 0, stream>>>(attnP, fc2b, mask, attnT);
    } else {
        k_gemm_b<64, 64, 0, 1><<<dim3(16, 16), 256, 0, stream>>>(
            fc1T, fc2wb, fc2b, mask, attnT, 4096, 4096, 128);
    }

    // main: out[m][t] = gelu(x·attnT^T), fp32 store
    if (has_xb) {
        k_cvt<<<24576, 256, 0, stream>>>(x, xb, 6291456);
        k_gemm2<<<dim3(8, 384), 256, 0, stream>>>(xb, attnT, (float*)d_out);
    } else {
        k_gemm_f32a<<<dim3(8, 384), 256, 0, stream>>>(x, attnT, (float*)d_out, 1024, 1024, 32);
    }
}